// Round 12
// baseline (116.638 us; speedup 1.0000x reference)
//
#include <hip/hip_runtime.h>
#include <cmath>

namespace {
constexpr int Cc = 256, CKc = 32, CVc = 32, KKc = 9;
constexpr int Bc = 8, Hc = 128, Wc = 128, HWc = Hc * Wc;

typedef __attribute__((ext_vector_type(8))) short   s16x8;
typedef __attribute__((ext_vector_type(8))) __bf16  bf16x8;
typedef __attribute__((ext_vector_type(4))) float   f32x4;

__device__ inline unsigned short f2bf(float f) {   // RNE f32 -> bf16 bits
    union { float f; unsigned u; } v; v.f = f;
    unsigned u = v.u + 0x7fffu + ((v.u >> 16) & 1u);
    return (unsigned short)(u >> 16);
}
}

// ---- Kernel 1: k1 = relu(W_k1 x + b), v = W_v x + b  via bf16 MFMA ----
// Outputs PX-MAJOR bf16: k1pm/vpm [b][hw][32]. Block 0 also converts o_w -> bf16.
__global__ __launch_bounds__(256) void ns_k1v(
    const float* __restrict__ x,
    const float* __restrict__ k1_w, const float* __restrict__ k1_b,
    const float* __restrict__ v_w,  const float* __restrict__ v_b,
    const float* __restrict__ o_w,
    unsigned short* __restrict__ k1pm, unsigned short* __restrict__ vpm,
    unsigned short* __restrict__ owbf)
{
    constexpr int LP = 72;                      // row stride (shorts): 144 B
    __shared__ short w_bf[64][LP];              // chunk of W (64 o x 64 ch)
    __shared__ short x_bf[128][LP];             // chunk of X (128 px x 64 ch)

    const int tid = threadIdx.x;
    const int l   = tid & 63;
    const int li  = l & 15;
    const int lk  = l >> 4;
    const int wv  = __builtin_amdgcn_readfirstlane(tid >> 6);

    // one-time o_w -> bf16 (owbf consumed only after this kernel completes)
    if (blockIdx.x == 0) {
        for (int i = tid * 4; i < Cc * CVc; i += 256 * 4) {
            const float4 f = *(const float4*)(o_w + i);
            const unsigned a = (unsigned)f2bf(f.x) | ((unsigned)f2bf(f.y) << 16);
            const unsigned c = (unsigned)f2bf(f.z) | ((unsigned)f2bf(f.w) << 16);
            *(uint2*)(owbf + i) = make_uint2(a, c);
        }
    }

    const int flat0 = blockIdx.x * 128;
    const int b  = flat0 / HWc;
    const int pp = flat0 - b * HWc;
    const float* xb = x + (size_t)b * Cc * HWc + pp;

    const int spx  = tid & 127;                 // X staging: pixel row
    const int schh = tid >> 7;
    const int so   = tid & 63;                  // W staging: output row
    const int swc0 = (tid >> 6) * 16;
    const float* wsrc = (so < 32) ? (k1_w + (size_t)so * Cc)
                                  : (v_w + (size_t)(so - 32) * Cc);

    f32x4 acc[8];
    const f32x4 zero = {0.f, 0.f, 0.f, 0.f};
#pragma unroll
    for (int i = 0; i < 8; ++i) acc[i] = zero;

    for (int c0 = 0; c0 < Cc; c0 += 64) {
        __syncthreads();
        {
            alignas(16) short tmp[16];
#pragma unroll
            for (int f = 0; f < 4; ++f) {
                const float4 fv = *(const float4*)(wsrc + c0 + swc0 + f * 4);
                tmp[f*4+0] = f2bf(fv.x); tmp[f*4+1] = f2bf(fv.y);
                tmp[f*4+2] = f2bf(fv.z); tmp[f*4+3] = f2bf(fv.w);
            }
            *(s16x8*)&w_bf[so][swc0]     = *(const s16x8*)&tmp[0];
            *(s16x8*)&w_bf[so][swc0 + 8] = *(const s16x8*)&tmp[8];
        }
#pragma unroll
        for (int u = 0; u < 8; ++u) {
            const int ch = (schh * 8 + u) * 4;
            const float e0 = xb[(size_t)(c0 + ch + 0) * HWc + spx];
            const float e1 = xb[(size_t)(c0 + ch + 1) * HWc + spx];
            const float e2 = xb[(size_t)(c0 + ch + 2) * HWc + spx];
            const float e3 = xb[(size_t)(c0 + ch + 3) * HWc + spx];
            const unsigned p01 = (unsigned)f2bf(e0) | ((unsigned)f2bf(e1) << 16);
            const unsigned p23 = (unsigned)f2bf(e2) | ((unsigned)f2bf(e3) << 16);
            *(uint2*)&x_bf[spx][ch] = make_uint2(p01, p23);
        }
        __syncthreads();

#pragma unroll
        for (int ks = 0; ks < 2; ++ks) {
            const s16x8 ar = *(const s16x8*)&w_bf[wv * 16 + li][ks * 32 + lk * 8];
            const bf16x8 af = __builtin_bit_cast(bf16x8, ar);
#pragma unroll
            for (int pt = 0; pt < 8; ++pt) {
                const s16x8 br = *(const s16x8*)&x_bf[pt * 16 + li][ks * 32 + lk * 8];
                acc[pt] = __builtin_amdgcn_mfma_f32_16x16x32_bf16(
                    af, __builtin_bit_cast(bf16x8, br), acc[pt], 0, 0, 0);
            }
        }
    }

    const bool is_k = wv < 2;
    const int obase = wv * 16 + lk * 4;
    const int chq = is_k ? obase : obase - 32;
    float bias[4];
#pragma unroll
    for (int r = 0; r < 4; ++r)
        bias[r] = is_k ? k1_b[obase + r] : v_b[obase + r - 32];
    unsigned short* dstb = is_k ? k1pm : vpm;

#pragma unroll
    for (int pt = 0; pt < 8; ++pt) {
        const size_t row = (size_t)b * HWc + pp + pt * 16 + li;
        float v0 = acc[pt][0] + bias[0], v1 = acc[pt][1] + bias[1];
        float v2 = acc[pt][2] + bias[2], v3 = acc[pt][3] + bias[3];
        if (is_k) {
            v0 = fmaxf(v0, 0.f); v1 = fmaxf(v1, 0.f);
            v2 = fmaxf(v2, 0.f); v3 = fmaxf(v3, 0.f);
        }
        const unsigned p01 = (unsigned)f2bf(v0) | ((unsigned)f2bf(v1) << 16);
        const unsigned p23 = (unsigned)f2bf(v2) | ((unsigned)f2bf(v3) << 16);
        *(uint2*)(dstb + row * 32 + chq) = make_uint2(p01, p23);
    }
}

// ---- Kernel 2: y-gen. 256 thr / 128 px (one image row), 2 thr per pixel.
//      dw3x3 + 1x1->9 (partials via LDS) + softmax + unfold-agg -> ypm bf16. ----
__global__ __launch_bounds__(256) void ns_y(
    const unsigned short* __restrict__ k1pm,
    const unsigned short* __restrict__ vpm,
    const float* __restrict__ dw_w, const float* __restrict__ dw_b,
    const float* __restrict__ k3_w, const float* __restrict__ k3_b,
    unsigned short* __restrict__ ypm)
{
    __shared__ float plds[2][KKc][128];         // 9 KB partial logits
    __shared__ float dwt[KKc][CKc];
    __shared__ float k3s[KKc][CKc];
    __shared__ float dwbs[CKc];
    __shared__ float k3bs[KKc];

    const int tid = threadIdx.x;
    if (tid < CKc * KKc) {
        const int ck = tid / KKc, kk = tid - ck * KKc;
        dwt[kk][ck] = dw_w[tid];
        ((float*)k3s)[tid] = k3_w[tid];
    }
    for (int idx = 256 + tid; idx < CKc * KKc; idx += 256) {
        const int ck = idx / KKc, kk = idx - ck * KKc;
        dwt[kk][ck] = dw_w[idx];
        ((float*)k3s)[idx] = k3_w[idx];
    }
    if (tid < CKc) dwbs[tid] = dw_b[tid];
    if (tid < KKc) k3bs[tid] = k3_b[tid];
    __syncthreads();

    // XCD-bijective swizzle: nwg = 1024 = 8 * 128 -> chunk = 128
    const int bid = blockIdx.x;
    const int swz = (bid & 7) * 128 + (bid >> 3);

    const int pxi  = tid & 127;                 // pixel within row
    const int half = tid >> 7;                  // channel half
    const int cb   = half * 16;

    const int flat0 = swz * 128;
    const int b   = flat0 / HWc;
    const int row = flat0 - b * HWc;
    const int h   = row >> 7;                   // Wc == 128
    const int w   = pxi;
    const int p   = row + pxi;

    const unsigned short* k1b = k1pm + (size_t)b * HWc * 32;
    const unsigned short* vb  = vpm  + (size_t)b * HWc * 32;

    // ---- depthwise 3x3, own 16 channels ----
    float t[16];
#pragma unroll
    for (int e = 0; e < 16; ++e) t[e] = dwbs[cb + e];
#pragma unroll
    for (int i = 0; i < 3; ++i) {
        const int hh = h + i - 1;
#pragma unroll
        for (int j = 0; j < 3; ++j) {
            const int ww = w + j - 1;
            if (hh < 0 || hh >= Hc || ww < 0 || ww >= Wc) continue;
            const unsigned short* kr = k1b + (size_t)(hh * Wc + ww) * 32 + cb;
            const int ij = i * 3 + j;
#pragma unroll
            for (int qv = 0; qv < 2; ++qv) {
                const bf16x8 kv = __builtin_bit_cast(bf16x8, *(const s16x8*)(kr + qv * 8));
#pragma unroll
                for (int e = 0; e < 8; ++e)
                    t[qv * 8 + e] = fmaf((float)kv[e], dwt[ij][cb + qv * 8 + e],
                                         t[qv * 8 + e]);
            }
        }
    }

    // ---- partial 1x1 CK->9; exchange via LDS ----
#pragma unroll
    for (int kk = 0; kk < KKc; ++kk) {
        float a = (half == 0) ? k3bs[kk] : 0.f;
#pragma unroll
        for (int e = 0; e < 16; ++e)
            a = fmaf(k3s[kk][cb + e], t[e], a);
        plds[half][kk][pxi] = a;
    }
    __syncthreads();

    float logit[KKc];
#pragma unroll
    for (int kk = 0; kk < KKc; ++kk)
        logit[kk] = plds[0][kk][pxi] + plds[1][kk][pxi];

    float m = logit[0];
#pragma unroll
    for (int kk = 1; kk < KKc; ++kk) m = fmaxf(m, logit[kk]);
    float s = 0.f;
#pragma unroll
    for (int kk = 0; kk < KKc; ++kk) { logit[kk] = expf(logit[kk] - m); s += logit[kk]; }
    const float inv = 1.f / s;
#pragma unroll
    for (int kk = 0; kk < KKc; ++kk) logit[kk] *= inv;

    // ---- unfold-aggregate, own 16 v-channels ----
    float yv[16];
#pragma unroll
    for (int e = 0; e < 16; ++e) yv[e] = 0.f;
#pragma unroll
    for (int i = 0; i < 3; ++i) {
        const int hh = h + i - 1;
#pragma unroll
        for (int j = 0; j < 3; ++j) {
            const int ww = w + j - 1;
            if (hh < 0 || hh >= Hc || ww < 0 || ww >= Wc) continue;
            const unsigned short* vr = vb + (size_t)(hh * Wc + ww) * 32 + cb;
            const float wv = logit[i * 3 + j];
#pragma unroll
            for (int qv = 0; qv < 2; ++qv) {
                const bf16x8 vv = __builtin_bit_cast(bf16x8, *(const s16x8*)(vr + qv * 8));
#pragma unroll
                for (int e = 0; e < 8; ++e)
                    yv[qv * 8 + e] = fmaf(wv, (float)vv[e], yv[qv * 8 + e]);
            }
        }
    }

    // ---- write own half of y px-major bf16 (32 B) ----
    alignas(16) short ybf[16];
#pragma unroll
    for (int e = 0; e < 16; ++e) ybf[e] = (short)f2bf(yv[e]);
    unsigned short* yo = ypm + ((size_t)b * HWc + p) * 32 + cb;
    *(float4*)(yo)     = *(const float4*)&ybf[0];
    *(float4*)(yo + 8) = *(const float4*)&ybf[8];
}

// ---- Kernel 3: out conv + residual, pure streaming MFMA. 256 thr / 128 px.
//      No LDS, no barriers. Wave wvv: o-tiles [wvv*4, wvv*4+4). ----
__global__ __launch_bounds__(256) void ns_oconv(
    const float* __restrict__ x,
    const unsigned short* __restrict__ ypm,
    const unsigned short* __restrict__ owbf, const float* __restrict__ o_b,
    float* __restrict__ out)
{
    const int tid = threadIdx.x;
    const int wvv = tid >> 6;                   // 0..3
    const int l  = tid & 63;
    const int li = l & 15;
    const int lk = l >> 4;

    const int flat0 = blockIdx.x * 128;
    const int b  = flat0 / HWc;
    const int p0 = flat0 - b * HWc;

    const unsigned short* yb = ypm + ((size_t)b * HWc + p0) * 32;
    const float* xb0 = x + (size_t)b * Cc * HWc;
    float* ob0 = out + (size_t)b * Cc * HWc;

    // hoist the 4 o_w B-fragments + biases
    bf16x8 wfrag[4];
    float  bias[4];
    const float* xrow[4];
    float* orow[4];
#pragma unroll
    for (int i = 0; i < 4; ++i) {
        const int och = (wvv * 4 + i) * 16 + li;
        wfrag[i] = __builtin_bit_cast(bf16x8,
                     *(const s16x8*)(owbf + (size_t)och * 32 + lk * 8));
        bias[i] = o_b[och];
        xrow[i] = xb0 + (size_t)och * HWc;
        orow[i] = ob0 + (size_t)och * HWc;
    }

#pragma unroll
    for (int pt = 0; pt < 8; ++pt) {
        const bf16x8 yfrag = __builtin_bit_cast(bf16x8,
            *(const s16x8*)(yb + (size_t)(pt * 16 + li) * 32 + lk * 8));
        const int px0 = p0 + pt * 16 + lk * 4;
#pragma unroll
        for (int i = 0; i < 4; ++i) {
            f32x4 acc = {0.f, 0.f, 0.f, 0.f};
            acc = __builtin_amdgcn_mfma_f32_16x16x32_bf16(yfrag, wfrag[i], acc, 0, 0, 0);
            const float4 xv = *(const float4*)(xrow[i] + px0);
            float4 ov;
            ov.x = xv.x + acc[0] + bias[i];
            ov.y = xv.y + acc[1] + bias[i];
            ov.z = xv.z + acc[2] + bias[i];
            ov.w = xv.w + acc[3] + bias[i];
            *(float4*)(orow[i] + px0) = ov;
        }
    }
}

extern "C" void kernel_launch(void* const* d_in, const int* in_sizes, int n_in,
                              void* d_out, int out_size, void* d_ws, size_t ws_size,
                              hipStream_t stream)
{
    const float* x    = (const float*)d_in[0];
    const float* k1_w = (const float*)d_in[1];
    const float* k1_b = (const float*)d_in[2];
    const float* dw_w = (const float*)d_in[3];
    const float* dw_b = (const float*)d_in[4];
    const float* k3_w = (const float*)d_in[5];
    const float* k3_b = (const float*)d_in[6];
    const float* v_w  = (const float*)d_in[7];
    const float* v_b  = (const float*)d_in[8];
    const float* o_w  = (const float*)d_in[9];
    const float* o_b  = (const float*)d_in[10];
    float* out = (float*)d_out;

    // workspace: k1pm (8.4MB) | vpm (8.4MB) | ypm (8.4MB) | owbf (16KB), bf16
    unsigned short* k1pm = (unsigned short*)d_ws;
    unsigned short* vpm  = k1pm + (size_t)Bc * HWc * 32;
    unsigned short* ypm  = vpm  + (size_t)Bc * HWc * 32;
    unsigned short* owbf = ypm  + (size_t)Bc * HWc * 32;

    const int npx = Bc * HWc;                   // 131072

    ns_k1v  <<<dim3(npx / 128), dim3(256), 0, stream>>>(x, k1_w, k1_b, v_w, v_b, o_w,
                                                        k1pm, vpm, owbf);
    ns_y    <<<dim3(npx / 128), dim3(256), 0, stream>>>(k1pm, vpm, dw_w, dw_b,
                                                        k3_w, k3_b, ypm);
    ns_oconv<<<dim3(npx / 128), dim3(256), 0, stream>>>(x, ypm, owbf, o_b, out);
}

// Round 13
// 106.664 us; speedup vs baseline: 1.0935x; 1.0935x over previous
//
#include <hip/hip_runtime.h>
#include <cmath>

namespace {
constexpr int Cc = 256, CKc = 32, CVc = 32, KKc = 9;
constexpr int Bc = 8, Hc = 128, Wc = 128, HWc = Hc * Wc;

typedef __attribute__((ext_vector_type(8))) short   s16x8;
typedef __attribute__((ext_vector_type(8))) __bf16  bf16x8;
typedef __attribute__((ext_vector_type(4))) float   f32x4;

__device__ inline unsigned short f2bf(float f) {   // RNE f32 -> bf16 bits
    union { float f; unsigned u; } v; v.f = f;
    unsigned u = v.u + 0x7fffu + ((v.u >> 16) & 1u);
    return (unsigned short)(u >> 16);
}
}

// ---- Kernel 1: k1 = relu(W_k1 x + b), v = W_v x + b  via bf16 MFMA ----
// Outputs PX-MAJOR bf16: k1pm/vpm [b][hw][32]. Block 0 also converts o_w -> bf16.
__global__ __launch_bounds__(256) void ns_k1v(
    const float* __restrict__ x,
    const float* __restrict__ k1_w, const float* __restrict__ k1_b,
    const float* __restrict__ v_w,  const float* __restrict__ v_b,
    const float* __restrict__ o_w,
    unsigned short* __restrict__ k1pm, unsigned short* __restrict__ vpm,
    unsigned short* __restrict__ owbf)
{
    constexpr int LP = 72;                      // row stride (shorts): 144 B
    __shared__ short w_bf[64][LP];              // chunk of W (64 o x 64 ch)
    __shared__ short x_bf[128][LP];             // chunk of X (128 px x 64 ch)

    const int tid = threadIdx.x;
    const int l   = tid & 63;
    const int li  = l & 15;
    const int lk  = l >> 4;
    const int wv  = __builtin_amdgcn_readfirstlane(tid >> 6);

    // one-time o_w -> bf16 (owbf consumed only after this kernel completes)
    if (blockIdx.x == 0) {
        for (int i = tid * 4; i < Cc * CVc; i += 256 * 4) {
            const float4 f = *(const float4*)(o_w + i);
            const unsigned a = (unsigned)f2bf(f.x) | ((unsigned)f2bf(f.y) << 16);
            const unsigned c = (unsigned)f2bf(f.z) | ((unsigned)f2bf(f.w) << 16);
            *(uint2*)(owbf + i) = make_uint2(a, c);
        }
    }

    const int flat0 = blockIdx.x * 128;
    const int b  = flat0 / HWc;
    const int pp = flat0 - b * HWc;
    const float* xb = x + (size_t)b * Cc * HWc + pp;

    const int spx  = tid & 127;                 // X staging: pixel row
    const int schh = tid >> 7;
    const int so   = tid & 63;                  // W staging: output row
    const int swc0 = (tid >> 6) * 16;
    const float* wsrc = (so < 32) ? (k1_w + (size_t)so * Cc)
                                  : (v_w + (size_t)(so - 32) * Cc);

    f32x4 acc[8];
    const f32x4 zero = {0.f, 0.f, 0.f, 0.f};
#pragma unroll
    for (int i = 0; i < 8; ++i) acc[i] = zero;

    for (int c0 = 0; c0 < Cc; c0 += 64) {
        __syncthreads();
        {
            alignas(16) short tmp[16];
#pragma unroll
            for (int f = 0; f < 4; ++f) {
                const float4 fv = *(const float4*)(wsrc + c0 + swc0 + f * 4);
                tmp[f*4+0] = f2bf(fv.x); tmp[f*4+1] = f2bf(fv.y);
                tmp[f*4+2] = f2bf(fv.z); tmp[f*4+3] = f2bf(fv.w);
            }
            *(s16x8*)&w_bf[so][swc0]     = *(const s16x8*)&tmp[0];
            *(s16x8*)&w_bf[so][swc0 + 8] = *(const s16x8*)&tmp[8];
        }
#pragma unroll
        for (int u = 0; u < 8; ++u) {
            const int ch = (schh * 8 + u) * 4;
            const float e0 = xb[(size_t)(c0 + ch + 0) * HWc + spx];
            const float e1 = xb[(size_t)(c0 + ch + 1) * HWc + spx];
            const float e2 = xb[(size_t)(c0 + ch + 2) * HWc + spx];
            const float e3 = xb[(size_t)(c0 + ch + 3) * HWc + spx];
            const unsigned p01 = (unsigned)f2bf(e0) | ((unsigned)f2bf(e1) << 16);
            const unsigned p23 = (unsigned)f2bf(e2) | ((unsigned)f2bf(e3) << 16);
            *(uint2*)&x_bf[spx][ch] = make_uint2(p01, p23);
        }
        __syncthreads();

#pragma unroll
        for (int ks = 0; ks < 2; ++ks) {
            const s16x8 ar = *(const s16x8*)&w_bf[wv * 16 + li][ks * 32 + lk * 8];
            const bf16x8 af = __builtin_bit_cast(bf16x8, ar);
#pragma unroll
            for (int pt = 0; pt < 8; ++pt) {
                const s16x8 br = *(const s16x8*)&x_bf[pt * 16 + li][ks * 32 + lk * 8];
                acc[pt] = __builtin_amdgcn_mfma_f32_16x16x32_bf16(
                    af, __builtin_bit_cast(bf16x8, br), acc[pt], 0, 0, 0);
            }
        }
    }

    const bool is_k = wv < 2;
    const int obase = wv * 16 + lk * 4;
    const int chq = is_k ? obase : obase - 32;
    float bias[4];
#pragma unroll
    for (int r = 0; r < 4; ++r)
        bias[r] = is_k ? k1_b[obase + r] : v_b[obase + r - 32];
    unsigned short* dstb = is_k ? k1pm : vpm;

#pragma unroll
    for (int pt = 0; pt < 8; ++pt) {
        const size_t row = (size_t)b * HWc + pp + pt * 16 + li;
        float v0 = acc[pt][0] + bias[0], v1 = acc[pt][1] + bias[1];
        float v2 = acc[pt][2] + bias[2], v3 = acc[pt][3] + bias[3];
        if (is_k) {
            v0 = fmaxf(v0, 0.f); v1 = fmaxf(v1, 0.f);
            v2 = fmaxf(v2, 0.f); v3 = fmaxf(v3, 0.f);
        }
        const unsigned p01 = (unsigned)f2bf(v0) | ((unsigned)f2bf(v1) << 16);
        const unsigned p23 = (unsigned)f2bf(v2) | ((unsigned)f2bf(v3) << 16);
        *(uint2*)(dstb + row * 32 + chq) = make_uint2(p01, p23);
    }
}

// ---- Kernel 2: y-gen. 256 thr / 128 px (one image row), 2 thr per pixel.
//      dw3x3 + 1x1->9 (partials via LDS) + softmax + unfold-agg -> ypm bf16. ----
__global__ __launch_bounds__(256) void ns_y(
    const unsigned short* __restrict__ k1pm,
    const unsigned short* __restrict__ vpm,
    const float* __restrict__ dw_w, const float* __restrict__ dw_b,
    const float* __restrict__ k3_w, const float* __restrict__ k3_b,
    unsigned short* __restrict__ ypm)
{
    __shared__ float plds[2][KKc][128];         // 9 KB partial logits
    __shared__ float dwt[KKc][CKc];
    __shared__ float k3s[KKc][CKc];
    __shared__ float dwbs[CKc];
    __shared__ float k3bs[KKc];

    const int tid = threadIdx.x;
    if (tid < CKc * KKc) {
        const int ck = tid / KKc, kk = tid - ck * KKc;
        dwt[kk][ck] = dw_w[tid];
        ((float*)k3s)[tid] = k3_w[tid];
    }
    for (int idx = 256 + tid; idx < CKc * KKc; idx += 256) {
        const int ck = idx / KKc, kk = idx - ck * KKc;
        dwt[kk][ck] = dw_w[idx];
        ((float*)k3s)[idx] = k3_w[idx];
    }
    if (tid < CKc) dwbs[tid] = dw_b[tid];
    if (tid < KKc) k3bs[tid] = k3_b[tid];
    __syncthreads();

    // XCD-bijective swizzle: nwg = 1024 = 8 * 128 -> chunk = 128
    const int bid = blockIdx.x;
    const int swz = (bid & 7) * 128 + (bid >> 3);

    const int pxi  = tid & 127;                 // pixel within row
    const int half = tid >> 7;                  // channel half
    const int cb   = half * 16;

    const int flat0 = swz * 128;
    const int b   = flat0 / HWc;
    const int row = flat0 - b * HWc;
    const int h   = row >> 7;                   // Wc == 128
    const int w   = pxi;
    const int p   = row + pxi;

    const unsigned short* k1b = k1pm + (size_t)b * HWc * 32;
    const unsigned short* vb  = vpm  + (size_t)b * HWc * 32;

    // ---- depthwise 3x3, own 16 channels ----
    float t[16];
#pragma unroll
    for (int e = 0; e < 16; ++e) t[e] = dwbs[cb + e];
#pragma unroll
    for (int i = 0; i < 3; ++i) {
        const int hh = h + i - 1;
#pragma unroll
        for (int j = 0; j < 3; ++j) {
            const int ww = w + j - 1;
            if (hh < 0 || hh >= Hc || ww < 0 || ww >= Wc) continue;
            const unsigned short* kr = k1b + (size_t)(hh * Wc + ww) * 32 + cb;
            const int ij = i * 3 + j;
#pragma unroll
            for (int qv = 0; qv < 2; ++qv) {
                const bf16x8 kv = __builtin_bit_cast(bf16x8, *(const s16x8*)(kr + qv * 8));
#pragma unroll
                for (int e = 0; e < 8; ++e)
                    t[qv * 8 + e] = fmaf((float)kv[e], dwt[ij][cb + qv * 8 + e],
                                         t[qv * 8 + e]);
            }
        }
    }

    // ---- partial 1x1 CK->9; exchange via LDS ----
#pragma unroll
    for (int kk = 0; kk < KKc; ++kk) {
        float a = (half == 0) ? k3bs[kk] : 0.f;
#pragma unroll
        for (int e = 0; e < 16; ++e)
            a = fmaf(k3s[kk][cb + e], t[e], a);
        plds[half][kk][pxi] = a;
    }
    __syncthreads();

    float logit[KKc];
#pragma unroll
    for (int kk = 0; kk < KKc; ++kk)
        logit[kk] = plds[0][kk][pxi] + plds[1][kk][pxi];

    float m = logit[0];
#pragma unroll
    for (int kk = 1; kk < KKc; ++kk) m = fmaxf(m, logit[kk]);
    float s = 0.f;
#pragma unroll
    for (int kk = 0; kk < KKc; ++kk) { logit[kk] = expf(logit[kk] - m); s += logit[kk]; }
    const float inv = 1.f / s;
#pragma unroll
    for (int kk = 0; kk < KKc; ++kk) logit[kk] *= inv;

    // ---- unfold-aggregate, own 16 v-channels ----
    float yv[16];
#pragma unroll
    for (int e = 0; e < 16; ++e) yv[e] = 0.f;
#pragma unroll
    for (int i = 0; i < 3; ++i) {
        const int hh = h + i - 1;
#pragma unroll
        for (int j = 0; j < 3; ++j) {
            const int ww = w + j - 1;
            if (hh < 0 || hh >= Hc || ww < 0 || ww >= Wc) continue;
            const unsigned short* vr = vb + (size_t)(hh * Wc + ww) * 32 + cb;
            const float wv = logit[i * 3 + j];
#pragma unroll
            for (int qv = 0; qv < 2; ++qv) {
                const bf16x8 vv = __builtin_bit_cast(bf16x8, *(const s16x8*)(vr + qv * 8));
#pragma unroll
                for (int e = 0; e < 8; ++e)
                    yv[qv * 8 + e] = fmaf(wv, (float)vv[e], yv[qv * 8 + e]);
            }
        }
    }

    // ---- write own half of y px-major bf16 (32 B) ----
    alignas(16) short ybf[16];
#pragma unroll
    for (int e = 0; e < 16; ++e) ybf[e] = (short)f2bf(yv[e]);
    unsigned short* yo = ypm + ((size_t)b * HWc + p) * 32 + cb;
    *(float4*)(yo)     = *(const float4*)&ybf[0];
    *(float4*)(yo + 8) = *(const float4*)&ybf[8];
}

// ---- Kernel 3: out conv + residual, streaming MFMA with BATCHED loads.
//      64 px/block, 2048 blocks. All 20 loads issued before compute/stores. ----
__global__ __launch_bounds__(256, 4) void ns_oconv(
    const float* __restrict__ x,
    const unsigned short* __restrict__ ypm,
    const unsigned short* __restrict__ owbf, const float* __restrict__ o_b,
    float* __restrict__ out)
{
    const int tid = threadIdx.x;
    const int wvv = tid >> 6;                   // 0..3
    const int l  = tid & 63;
    const int li = l & 15;
    const int lk = l >> 4;

    const int flat0 = blockIdx.x * 64;          // 64 px per block
    const int b  = flat0 / HWc;
    const int p0 = flat0 - b * HWc;

    const unsigned short* yb = ypm + ((size_t)b * HWc + p0) * 32;
    const float* xb0 = x + (size_t)b * Cc * HWc;
    float* ob0 = out + (size_t)b * Cc * HWc;

    // o_w fragments + biases (owbf is 16 KB, L2-resident)
    bf16x8 wfrag[4];
    float  bias[4];
    const float* xrow[4];
    float* orow[4];
#pragma unroll
    for (int i = 0; i < 4; ++i) {
        const int och = (wvv * 4 + i) * 16 + li;
        wfrag[i] = __builtin_bit_cast(bf16x8,
                     *(const s16x8*)(owbf + (size_t)och * 32 + lk * 8));
        bias[i] = o_b[och];
        xrow[i] = xb0 + (size_t)och * HWc + p0 + lk * 4;
        orow[i] = ob0 + (size_t)och * HWc + p0 + lk * 4;
    }

    // ---- batch ALL loads: 4 y-frags + 16 x float4 (20 x 16B in flight) ----
    bf16x8 yfrag[4];
#pragma unroll
    for (int pt = 0; pt < 4; ++pt)
        yfrag[pt] = __builtin_bit_cast(bf16x8,
            *(const s16x8*)(yb + (size_t)(pt * 16 + li) * 32 + lk * 8));

    float4 xv0[4], xv1[4], xv2[4], xv3[4];
#pragma unroll
    for (int pt = 0; pt < 4; ++pt) {
        xv0[pt] = *(const float4*)(xrow[0] + pt * 16);
        xv1[pt] = *(const float4*)(xrow[1] + pt * 16);
        xv2[pt] = *(const float4*)(xrow[2] + pt * 16);
        xv3[pt] = *(const float4*)(xrow[3] + pt * 16);
    }

    // ---- compute + store ----
#pragma unroll
    for (int pt = 0; pt < 4; ++pt) {
        {
            f32x4 acc = {0.f, 0.f, 0.f, 0.f};
            acc = __builtin_amdgcn_mfma_f32_16x16x32_bf16(yfrag[pt], wfrag[0], acc, 0, 0, 0);
            float4 ov = { xv0[pt].x + acc[0] + bias[0], xv0[pt].y + acc[1] + bias[0],
                          xv0[pt].z + acc[2] + bias[0], xv0[pt].w + acc[3] + bias[0] };
            *(float4*)(orow[0] + pt * 16) = ov;
        }
        {
            f32x4 acc = {0.f, 0.f, 0.f, 0.f};
            acc = __builtin_amdgcn_mfma_f32_16x16x32_bf16(yfrag[pt], wfrag[1], acc, 0, 0, 0);
            float4 ov = { xv1[pt].x + acc[0] + bias[1], xv1[pt].y + acc[1] + bias[1],
                          xv1[pt].z + acc[2] + bias[1], xv1[pt].w + acc[3] + bias[1] };
            *(float4*)(orow[1] + pt * 16) = ov;
        }
        {
            f32x4 acc = {0.f, 0.f, 0.f, 0.f};
            acc = __builtin_amdgcn_mfma_f32_16x16x32_bf16(yfrag[pt], wfrag[2], acc, 0, 0, 0);
            float4 ov = { xv2[pt].x + acc[0] + bias[2], xv2[pt].y + acc[1] + bias[2],
                          xv2[pt].z + acc[2] + bias[2], xv2[pt].w + acc[3] + bias[2] };
            *(float4*)(orow[2] + pt * 16) = ov;
        }
        {
            f32x4 acc = {0.f, 0.f, 0.f, 0.f};
            acc = __builtin_amdgcn_mfma_f32_16x16x32_bf16(yfrag[pt], wfrag[3], acc, 0, 0, 0);
            float4 ov = { xv3[pt].x + acc[0] + bias[3], xv3[pt].y + acc[1] + bias[3],
                          xv3[pt].z + acc[2] + bias[3], xv3[pt].w + acc[3] + bias[3] };
            *(float4*)(orow[3] + pt * 16) = ov;
        }
    }
}

extern "C" void kernel_launch(void* const* d_in, const int* in_sizes, int n_in,
                              void* d_out, int out_size, void* d_ws, size_t ws_size,
                              hipStream_t stream)
{
    const float* x    = (const float*)d_in[0];
    const float* k1_w = (const float*)d_in[1];
    const float* k1_b = (const float*)d_in[2];
    const float* dw_w = (const float*)d_in[3];
    const float* dw_b = (const float*)d_in[4];
    const float* k3_w = (const float*)d_in[5];
    const float* k3_b = (const float*)d_in[6];
    const float* v_w  = (const float*)d_in[7];
    const float* v_b  = (const float*)d_in[8];
    const float* o_w  = (const float*)d_in[9];
    const float* o_b  = (const float*)d_in[10];
    float* out = (float*)d_out;

    // workspace: k1pm (8.4MB) | vpm (8.4MB) | ypm (8.4MB) | owbf (16KB), bf16
    unsigned short* k1pm = (unsigned short*)d_ws;
    unsigned short* vpm  = k1pm + (size_t)Bc * HWc * 32;
    unsigned short* ypm  = vpm  + (size_t)Bc * HWc * 32;
    unsigned short* owbf = ypm  + (size_t)Bc * HWc * 32;

    const int npx = Bc * HWc;                   // 131072

    ns_k1v  <<<dim3(npx / 128), dim3(256), 0, stream>>>(x, k1_w, k1_b, v_w, v_b, o_w,
                                                        k1pm, vpm, owbf);
    ns_y    <<<dim3(npx / 128), dim3(256), 0, stream>>>(k1pm, vpm, dw_w, dw_b,
                                                        k3_w, k3_b, ypm);
    ns_oconv<<<dim3(npx / 64), dim3(256), 0, stream>>>(x, ypm, owbf, o_b, out);
}

// Round 14
// 93.913 us; speedup vs baseline: 1.2420x; 1.1358x over previous
//
#include <hip/hip_runtime.h>
#include <cmath>

namespace {
constexpr int Cc = 256, CKc = 32, CVc = 32, KKc = 9;
constexpr int Bc = 8, Hc = 128, Wc = 128, HWc = Hc * Wc;

typedef __attribute__((ext_vector_type(8))) short   s16x8;
typedef __attribute__((ext_vector_type(8))) __bf16  bf16x8;
typedef __attribute__((ext_vector_type(4))) float   f32x4;

__device__ inline unsigned short f2bf(float f) {   // RNE f32 -> bf16 bits
    union { float f; unsigned u; } v; v.f = f;
    unsigned u = v.u + 0x7fffu + ((v.u >> 16) & 1u);
    return (unsigned short)(u >> 16);
}
}

// ---- Kernel 1: k1 = relu(W_k1 x + b), v = W_v x + b  via bf16 MFMA ----
// Outputs PX-MAJOR bf16: k1pm/vpm [b][hw][32]. Block 0 also converts o_w -> bf16.
__global__ __launch_bounds__(256) void ns_k1v(
    const float* __restrict__ x,
    const float* __restrict__ k1_w, const float* __restrict__ k1_b,
    const float* __restrict__ v_w,  const float* __restrict__ v_b,
    const float* __restrict__ o_w,
    unsigned short* __restrict__ k1pm, unsigned short* __restrict__ vpm,
    unsigned short* __restrict__ owbf)
{
    constexpr int LP = 72;                      // row stride (shorts): 144 B
    __shared__ short w_bf[64][LP];              // chunk of W (64 o x 64 ch)
    __shared__ short x_bf[128][LP];             // chunk of X (128 px x 64 ch)

    const int tid = threadIdx.x;
    const int l   = tid & 63;
    const int li  = l & 15;
    const int lk  = l >> 4;
    const int wv  = __builtin_amdgcn_readfirstlane(tid >> 6);

    // one-time o_w -> bf16 (owbf consumed only after this kernel completes)
    if (blockIdx.x == 0) {
        for (int i = tid * 4; i < Cc * CVc; i += 256 * 4) {
            const float4 f = *(const float4*)(o_w + i);
            const unsigned a = (unsigned)f2bf(f.x) | ((unsigned)f2bf(f.y) << 16);
            const unsigned c = (unsigned)f2bf(f.z) | ((unsigned)f2bf(f.w) << 16);
            *(uint2*)(owbf + i) = make_uint2(a, c);
        }
    }

    const int flat0 = blockIdx.x * 128;
    const int b  = flat0 / HWc;
    const int pp = flat0 - b * HWc;
    const float* xb = x + (size_t)b * Cc * HWc + pp;

    const int spx  = tid & 127;                 // X staging: pixel row
    const int schh = tid >> 7;
    const int so   = tid & 63;                  // W staging: output row
    const int swc0 = (tid >> 6) * 16;
    const float* wsrc = (so < 32) ? (k1_w + (size_t)so * Cc)
                                  : (v_w + (size_t)(so - 32) * Cc);

    f32x4 acc[8];
    const f32x4 zero = {0.f, 0.f, 0.f, 0.f};
#pragma unroll
    for (int i = 0; i < 8; ++i) acc[i] = zero;

    for (int c0 = 0; c0 < Cc; c0 += 64) {
        __syncthreads();
        {
            alignas(16) short tmp[16];
#pragma unroll
            for (int f = 0; f < 4; ++f) {
                const float4 fv = *(const float4*)(wsrc + c0 + swc0 + f * 4);
                tmp[f*4+0] = f2bf(fv.x); tmp[f*4+1] = f2bf(fv.y);
                tmp[f*4+2] = f2bf(fv.z); tmp[f*4+3] = f2bf(fv.w);
            }
            *(s16x8*)&w_bf[so][swc0]     = *(const s16x8*)&tmp[0];
            *(s16x8*)&w_bf[so][swc0 + 8] = *(const s16x8*)&tmp[8];
        }
#pragma unroll
        for (int u = 0; u < 8; ++u) {
            const int ch = (schh * 8 + u) * 4;
            const float e0 = xb[(size_t)(c0 + ch + 0) * HWc + spx];
            const float e1 = xb[(size_t)(c0 + ch + 1) * HWc + spx];
            const float e2 = xb[(size_t)(c0 + ch + 2) * HWc + spx];
            const float e3 = xb[(size_t)(c0 + ch + 3) * HWc + spx];
            const unsigned p01 = (unsigned)f2bf(e0) | ((unsigned)f2bf(e1) << 16);
            const unsigned p23 = (unsigned)f2bf(e2) | ((unsigned)f2bf(e3) << 16);
            *(uint2*)&x_bf[spx][ch] = make_uint2(p01, p23);
        }
        __syncthreads();

#pragma unroll
        for (int ks = 0; ks < 2; ++ks) {
            const s16x8 ar = *(const s16x8*)&w_bf[wv * 16 + li][ks * 32 + lk * 8];
            const bf16x8 af = __builtin_bit_cast(bf16x8, ar);
#pragma unroll
            for (int pt = 0; pt < 8; ++pt) {
                const s16x8 br = *(const s16x8*)&x_bf[pt * 16 + li][ks * 32 + lk * 8];
                acc[pt] = __builtin_amdgcn_mfma_f32_16x16x32_bf16(
                    af, __builtin_bit_cast(bf16x8, br), acc[pt], 0, 0, 0);
            }
        }
    }

    const bool is_k = wv < 2;
    const int obase = wv * 16 + lk * 4;
    const int chq = is_k ? obase : obase - 32;
    float bias[4];
#pragma unroll
    for (int r = 0; r < 4; ++r)
        bias[r] = is_k ? k1_b[obase + r] : v_b[obase + r - 32];
    unsigned short* dstb = is_k ? k1pm : vpm;

#pragma unroll
    for (int pt = 0; pt < 8; ++pt) {
        const size_t row = (size_t)b * HWc + pp + pt * 16 + li;
        float v0 = acc[pt][0] + bias[0], v1 = acc[pt][1] + bias[1];
        float v2 = acc[pt][2] + bias[2], v3 = acc[pt][3] + bias[3];
        if (is_k) {
            v0 = fmaxf(v0, 0.f); v1 = fmaxf(v1, 0.f);
            v2 = fmaxf(v2, 0.f); v3 = fmaxf(v3, 0.f);
        }
        const unsigned p01 = (unsigned)f2bf(v0) | ((unsigned)f2bf(v1) << 16);
        const unsigned p23 = (unsigned)f2bf(v2) | ((unsigned)f2bf(v3) << 16);
        *(uint2*)(dstb + row * 32 + chq) = make_uint2(p01, p23);
    }
}

// ---- Kernel 2: y-gen. 256 thr / 128 px (one image row), 2 thr per pixel.
//      dw3x3 + 1x1->9 (partials via LDS) + softmax + unfold-agg -> ypm bf16. ----
__global__ __launch_bounds__(256) void ns_y(
    const unsigned short* __restrict__ k1pm,
    const unsigned short* __restrict__ vpm,
    const float* __restrict__ dw_w, const float* __restrict__ dw_b,
    const float* __restrict__ k3_w, const float* __restrict__ k3_b,
    unsigned short* __restrict__ ypm)
{
    __shared__ float plds[2][KKc][128];         // 9 KB partial logits
    __shared__ float dwt[KKc][CKc];
    __shared__ float k3s[KKc][CKc];
    __shared__ float dwbs[CKc];
    __shared__ float k3bs[KKc];

    const int tid = threadIdx.x;
    if (tid < CKc * KKc) {
        const int ck = tid / KKc, kk = tid - ck * KKc;
        dwt[kk][ck] = dw_w[tid];
        ((float*)k3s)[tid] = k3_w[tid];
    }
    for (int idx = 256 + tid; idx < CKc * KKc; idx += 256) {
        const int ck = idx / KKc, kk = idx - ck * KKc;
        dwt[kk][ck] = dw_w[idx];
        ((float*)k3s)[idx] = k3_w[idx];
    }
    if (tid < CKc) dwbs[tid] = dw_b[tid];
    if (tid < KKc) k3bs[tid] = k3_b[tid];
    __syncthreads();

    // XCD-bijective swizzle: nwg = 1024 = 8 * 128 -> chunk = 128
    const int bid = blockIdx.x;
    const int swz = (bid & 7) * 128 + (bid >> 3);

    const int pxi  = tid & 127;                 // pixel within row
    const int half = tid >> 7;                  // channel half
    const int cb   = half * 16;

    const int flat0 = swz * 128;
    const int b   = flat0 / HWc;
    const int row = flat0 - b * HWc;
    const int h   = row >> 7;                   // Wc == 128
    const int w   = pxi;
    const int p   = row + pxi;

    const unsigned short* k1b = k1pm + (size_t)b * HWc * 32;
    const unsigned short* vb  = vpm  + (size_t)b * HWc * 32;

    // ---- depthwise 3x3, own 16 channels ----
    float t[16];
#pragma unroll
    for (int e = 0; e < 16; ++e) t[e] = dwbs[cb + e];
#pragma unroll
    for (int i = 0; i < 3; ++i) {
        const int hh = h + i - 1;
#pragma unroll
        for (int j = 0; j < 3; ++j) {
            const int ww = w + j - 1;
            if (hh < 0 || hh >= Hc || ww < 0 || ww >= Wc) continue;
            const unsigned short* kr = k1b + (size_t)(hh * Wc + ww) * 32 + cb;
            const int ij = i * 3 + j;
#pragma unroll
            for (int qv = 0; qv < 2; ++qv) {
                const bf16x8 kv = __builtin_bit_cast(bf16x8, *(const s16x8*)(kr + qv * 8));
#pragma unroll
                for (int e = 0; e < 8; ++e)
                    t[qv * 8 + e] = fmaf((float)kv[e], dwt[ij][cb + qv * 8 + e],
                                         t[qv * 8 + e]);
            }
        }
    }

    // ---- partial 1x1 CK->9; exchange via LDS ----
#pragma unroll
    for (int kk = 0; kk < KKc; ++kk) {
        float a = (half == 0) ? k3bs[kk] : 0.f;
#pragma unroll
        for (int e = 0; e < 16; ++e)
            a = fmaf(k3s[kk][cb + e], t[e], a);
        plds[half][kk][pxi] = a;
    }
    __syncthreads();

    float logit[KKc];
#pragma unroll
    for (int kk = 0; kk < KKc; ++kk)
        logit[kk] = plds[0][kk][pxi] + plds[1][kk][pxi];

    float m = logit[0];
#pragma unroll
    for (int kk = 1; kk < KKc; ++kk) m = fmaxf(m, logit[kk]);
    float s = 0.f;
#pragma unroll
    for (int kk = 0; kk < KKc; ++kk) { logit[kk] = expf(logit[kk] - m); s += logit[kk]; }
    const float inv = 1.f / s;
#pragma unroll
    for (int kk = 0; kk < KKc; ++kk) logit[kk] *= inv;

    // ---- unfold-aggregate, own 16 v-channels ----
    float yv[16];
#pragma unroll
    for (int e = 0; e < 16; ++e) yv[e] = 0.f;
#pragma unroll
    for (int i = 0; i < 3; ++i) {
        const int hh = h + i - 1;
#pragma unroll
        for (int j = 0; j < 3; ++j) {
            const int ww = w + j - 1;
            if (hh < 0 || hh >= Hc || ww < 0 || ww >= Wc) continue;
            const unsigned short* vr = vb + (size_t)(hh * Wc + ww) * 32 + cb;
            const float wv = logit[i * 3 + j];
#pragma unroll
            for (int qv = 0; qv < 2; ++qv) {
                const bf16x8 vv = __builtin_bit_cast(bf16x8, *(const s16x8*)(vr + qv * 8));
#pragma unroll
                for (int e = 0; e < 8; ++e)
                    yv[qv * 8 + e] = fmaf(wv, (float)vv[e], yv[qv * 8 + e]);
            }
        }
    }

    // ---- write own half of y px-major bf16 (32 B) ----
    alignas(16) short ybf[16];
#pragma unroll
    for (int e = 0; e < 16; ++e) ybf[e] = (short)f2bf(yv[e]);
    unsigned short* yo = ypm + ((size_t)b * HWc + p) * 32 + cb;
    *(float4*)(yo)     = *(const float4*)&ybf[0];
    *(float4*)(yo + 8) = *(const float4*)&ybf[8];
}

// ---- Kernel 3: out conv + residual. 256 px/block, 512 blocks.
//      MFMA -> LDS transpose (per-wave, barrier-free) -> 1 KB contiguous
//      x-loads / out-stores. LDS 64 KB, XOR-swizzled cols. ----
__global__ __launch_bounds__(256, 2) void ns_oconv(
    const float* __restrict__ x,
    const unsigned short* __restrict__ ypm,
    const unsigned short* __restrict__ owbf, const float* __restrict__ o_b,
    float* __restrict__ out)
{
    __shared__ float dlds[64 * 256];            // 64 KB: [och_local][px], swizzled

    const int tid = threadIdx.x;
    const int w   = tid >> 6;                   // wave 0..3
    const int l   = tid & 63;
    const int li  = l & 15;
    const int lk  = l >> 4;

    const int flat0 = blockIdx.x * 256;
    const int b  = flat0 / HWc;
    const int p0 = flat0 - b * HWc;

    // ---- 16 y A-frags, loaded once (A[m=px][k=cv]: lane li = px row) ----
    const unsigned short* yb = ypm + ((size_t)b * HWc + p0) * 32;
    bf16x8 yfrag[16];
#pragma unroll
    for (int pt = 0; pt < 16; ++pt)
        yfrag[pt] = __builtin_bit_cast(bf16x8,
            *(const s16x8*)(yb + (size_t)(pt * 16 + li) * 32 + lk * 8));

    const float* xb0 = x + (size_t)b * Cc * HWc + p0;
    float* ob0 = out + (size_t)b * Cc * HWc + p0;

    for (int pass = 0; pass < 4; ++pass) {
        const int och0 = pass * 64;

        // ---- phase A: 16 MFMAs, D -> LDS rows [w*16 .. w*16+15] (own rows) ----
        const int rowA = w * 16 + li;           // lane's D column och (local)
        const bf16x8 wfrag = __builtin_bit_cast(bf16x8,
            *(const s16x8*)(owbf + (size_t)(och0 + rowA) * 32 + lk * 8));
        float* dro = dlds + rowA * 256;
        const int sw = (li & 7) << 2;           // XOR swizzle (16B-granular)
#pragma unroll
        for (int pt = 0; pt < 16; ++pt) {
            f32x4 acc = {0.f, 0.f, 0.f, 0.f};
            acc = __builtin_amdgcn_mfma_f32_16x16x32_bf16(yfrag[pt], wfrag, acc, 0, 0, 0);
            const int col = (pt * 16 + lk * 4) ^ sw;   // px = pt*16+lk*4 .. +3
            *(f32x4*)(dro + col) = acc;
        }
        // no barrier: each wave reads back only the rows it wrote (same-wave
        // DS ordering is HW-guaranteed)

        // ---- phase B: batched 1 KB-contiguous x-loads, LDS read, store ----
        float4 xvv[16];
#pragma unroll
        for (int r = 0; r < 16; ++r) {
            const int och = och0 + w * 16 + r;
            xvv[r] = *(const float4*)(xb0 + (size_t)och * HWc + l * 4);
        }
#pragma unroll
        for (int r = 0; r < 16; ++r) {
            const int row = w * 16 + r;
            const int och = och0 + row;
            const float bi = o_b[och];
            const int col = (l * 4) ^ ((row & 7) << 2);
            const f32x4 dv = *(const f32x4*)(dlds + row * 256 + col);
            float4 ov = { xvv[r].x + dv[0] + bi, xvv[r].y + dv[1] + bi,
                          xvv[r].z + dv[2] + bi, xvv[r].w + dv[3] + bi };
            *(float4*)(ob0 + (size_t)och * HWc + l * 4) = ov;
        }
    }
}

extern "C" void kernel_launch(void* const* d_in, const int* in_sizes, int n_in,
                              void* d_out, int out_size, void* d_ws, size_t ws_size,
                              hipStream_t stream)
{
    const float* x    = (const float*)d_in[0];
    const float* k1_w = (const float*)d_in[1];
    const float* k1_b = (const float*)d_in[2];
    const float* dw_w = (const float*)d_in[3];
    const float* dw_b = (const float*)d_in[4];
    const float* k3_w = (const float*)d_in[5];
    const float* k3_b = (const float*)d_in[6];
    const float* v_w  = (const float*)d_in[7];
    const float* v_b  = (const float*)d_in[8];
    const float* o_w  = (const float*)d_in[9];
    const float* o_b  = (const float*)d_in[10];
    float* out = (float*)d_out;

    // workspace: k1pm (8.4MB) | vpm (8.4MB) | ypm (8.4MB) | owbf (16KB), bf16
    unsigned short* k1pm = (unsigned short*)d_ws;
    unsigned short* vpm  = k1pm + (size_t)Bc * HWc * 32;
    unsigned short* ypm  = vpm  + (size_t)Bc * HWc * 32;
    unsigned short* owbf = ypm  + (size_t)Bc * HWc * 32;

    const int npx = Bc * HWc;                   // 131072

    ns_k1v  <<<dim3(npx / 128), dim3(256), 0, stream>>>(x, k1_w, k1_b, v_w, v_b, o_w,
                                                        k1pm, vpm, owbf);
    ns_y    <<<dim3(npx / 128), dim3(256), 0, stream>>>(k1pm, vpm, dw_w, dw_b,
                                                        k3_w, k3_b, ypm);
    ns_oconv<<<dim3(npx / 256), dim3(256), 0, stream>>>(x, ypm, owbf, o_b, out);
}

// Round 15
// 90.606 us; speedup vs baseline: 1.2873x; 1.0365x over previous
//
#include <hip/hip_runtime.h>
#include <cmath>

namespace {
constexpr int Cc = 256, CKc = 32, CVc = 32, KKc = 9;
constexpr int Bc = 8, Hc = 128, Wc = 128, HWc = Hc * Wc;

typedef __attribute__((ext_vector_type(8))) short   s16x8;
typedef __attribute__((ext_vector_type(8))) __bf16  bf16x8;
typedef __attribute__((ext_vector_type(4))) float   f32x4;

__device__ inline unsigned short f2bf(float f) {   // RNE f32 -> bf16 bits
    union { float f; unsigned u; } v; v.f = f;
    unsigned u = v.u + 0x7fffu + ((v.u >> 16) & 1u);
    return (unsigned short)(u >> 16);
}
}

// ---- Kernel 1: k1 = relu(W_k1 x + b), v = W_v x + b  via bf16 MFMA ----
// Outputs PX-MAJOR bf16: k1pm/vpm [b][hw][32]. Block 0 also converts o_w -> bf16.
__global__ __launch_bounds__(256) void ns_k1v(
    const float* __restrict__ x,
    const float* __restrict__ k1_w, const float* __restrict__ k1_b,
    const float* __restrict__ v_w,  const float* __restrict__ v_b,
    const float* __restrict__ o_w,
    unsigned short* __restrict__ k1pm, unsigned short* __restrict__ vpm,
    unsigned short* __restrict__ owbf)
{
    constexpr int LP = 72;                      // row stride (shorts): 144 B
    __shared__ short w_bf[64][LP];              // chunk of W (64 o x 64 ch)
    __shared__ short x_bf[128][LP];             // chunk of X (128 px x 64 ch)

    const int tid = threadIdx.x;
    const int l   = tid & 63;
    const int li  = l & 15;
    const int lk  = l >> 4;
    const int wv  = __builtin_amdgcn_readfirstlane(tid >> 6);

    // one-time o_w -> bf16 (owbf consumed only after this kernel completes)
    if (blockIdx.x == 0) {
        for (int i = tid * 4; i < Cc * CVc; i += 256 * 4) {
            const float4 f = *(const float4*)(o_w + i);
            const unsigned a = (unsigned)f2bf(f.x) | ((unsigned)f2bf(f.y) << 16);
            const unsigned c = (unsigned)f2bf(f.z) | ((unsigned)f2bf(f.w) << 16);
            *(uint2*)(owbf + i) = make_uint2(a, c);
        }
    }

    const int flat0 = blockIdx.x * 128;
    const int b  = flat0 / HWc;
    const int pp = flat0 - b * HWc;
    const float* xb = x + (size_t)b * Cc * HWc + pp;

    const int sp2 = (tid & 63) * 2;             // X staging: pixel pair base
    const int scg = tid >> 6;                   // X staging: ch group (16 ch)
    const int so   = tid & 63;                  // W staging: output row
    const int swc0 = (tid >> 6) * 16;
    const float* wsrc = (so < 32) ? (k1_w + (size_t)so * Cc)
                                  : (v_w + (size_t)(so - 32) * Cc);

    f32x4 acc[8];
    const f32x4 zero = {0.f, 0.f, 0.f, 0.f};
#pragma unroll
    for (int i = 0; i < 8; ++i) acc[i] = zero;

    for (int c0 = 0; c0 < Cc; c0 += 64) {
        __syncthreads();
        // ---- stage W chunk ----
        {
            alignas(16) short tmp[16];
#pragma unroll
            for (int f = 0; f < 4; ++f) {
                const float4 fv = *(const float4*)(wsrc + c0 + swc0 + f * 4);
                tmp[f*4+0] = f2bf(fv.x); tmp[f*4+1] = f2bf(fv.y);
                tmp[f*4+2] = f2bf(fv.z); tmp[f*4+3] = f2bf(fv.w);
            }
            *(s16x8*)&w_bf[so][swc0]     = *(const s16x8*)&tmp[0];
            *(s16x8*)&w_bf[so][swc0 + 8] = *(const s16x8*)&tmp[8];
        }
        // ---- stage X chunk: 2 px x 16 ch per thread, 16 batched float2 loads
        //      (512 B per wave-instruction), then pack + 4 ds_write_b128 ----
        {
            float2 xv2[16];
#pragma unroll
            for (int cq = 0; cq < 16; ++cq)
                xv2[cq] = *(const float2*)(xb + (size_t)(c0 + scg * 16 + cq) * HWc + sp2);
            alignas(16) short ta[16], tb[16];
#pragma unroll
            for (int cq = 0; cq < 16; ++cq) {
                ta[cq] = f2bf(xv2[cq].x);
                tb[cq] = f2bf(xv2[cq].y);
            }
            *(s16x8*)&x_bf[sp2    ][scg * 16]     = *(const s16x8*)&ta[0];
            *(s16x8*)&x_bf[sp2    ][scg * 16 + 8] = *(const s16x8*)&ta[8];
            *(s16x8*)&x_bf[sp2 + 1][scg * 16]     = *(const s16x8*)&tb[0];
            *(s16x8*)&x_bf[sp2 + 1][scg * 16 + 8] = *(const s16x8*)&tb[8];
        }
        __syncthreads();

#pragma unroll
        for (int ks = 0; ks < 2; ++ks) {
            const s16x8 ar = *(const s16x8*)&w_bf[wv * 16 + li][ks * 32 + lk * 8];
            const bf16x8 af = __builtin_bit_cast(bf16x8, ar);
#pragma unroll
            for (int pt = 0; pt < 8; ++pt) {
                const s16x8 br = *(const s16x8*)&x_bf[pt * 16 + li][ks * 32 + lk * 8];
                acc[pt] = __builtin_amdgcn_mfma_f32_16x16x32_bf16(
                    af, __builtin_bit_cast(bf16x8, br), acc[pt], 0, 0, 0);
            }
        }
    }

    const bool is_k = wv < 2;
    const int obase = wv * 16 + lk * 4;
    const int chq = is_k ? obase : obase - 32;
    float bias[4];
#pragma unroll
    for (int r = 0; r < 4; ++r)
        bias[r] = is_k ? k1_b[obase + r] : v_b[obase + r - 32];
    unsigned short* dstb = is_k ? k1pm : vpm;

#pragma unroll
    for (int pt = 0; pt < 8; ++pt) {
        const size_t row = (size_t)b * HWc + pp + pt * 16 + li;
        float v0 = acc[pt][0] + bias[0], v1 = acc[pt][1] + bias[1];
        float v2 = acc[pt][2] + bias[2], v3 = acc[pt][3] + bias[3];
        if (is_k) {
            v0 = fmaxf(v0, 0.f); v1 = fmaxf(v1, 0.f);
            v2 = fmaxf(v2, 0.f); v3 = fmaxf(v3, 0.f);
        }
        const unsigned p01 = (unsigned)f2bf(v0) | ((unsigned)f2bf(v1) << 16);
        const unsigned p23 = (unsigned)f2bf(v2) | ((unsigned)f2bf(v3) << 16);
        *(uint2*)(dstb + row * 32 + chq) = make_uint2(p01, p23);
    }
}

// ---- Kernel 2: y-gen. 256 thr / 128 px (one image row), 2 thr per pixel.
//      dw3x3 + 1x1->9 (partials via LDS) + softmax + unfold-agg -> ypm bf16. ----
__global__ __launch_bounds__(256) void ns_y(
    const unsigned short* __restrict__ k1pm,
    const unsigned short* __restrict__ vpm,
    const float* __restrict__ dw_w, const float* __restrict__ dw_b,
    const float* __restrict__ k3_w, const float* __restrict__ k3_b,
    unsigned short* __restrict__ ypm)
{
    __shared__ float plds[2][KKc][128];         // 9 KB partial logits
    __shared__ float dwt[KKc][CKc];
    __shared__ float k3s[KKc][CKc];
    __shared__ float dwbs[CKc];
    __shared__ float k3bs[KKc];

    const int tid = threadIdx.x;
    if (tid < CKc * KKc) {
        const int ck = tid / KKc, kk = tid - ck * KKc;
        dwt[kk][ck] = dw_w[tid];
        ((float*)k3s)[tid] = k3_w[tid];
    }
    for (int idx = 256 + tid; idx < CKc * KKc; idx += 256) {
        const int ck = idx / KKc, kk = idx - ck * KKc;
        dwt[kk][ck] = dw_w[idx];
        ((float*)k3s)[idx] = k3_w[idx];
    }
    if (tid < CKc) dwbs[tid] = dw_b[tid];
    if (tid < KKc) k3bs[tid] = k3_b[tid];
    __syncthreads();

    // XCD-bijective swizzle: nwg = 1024 = 8 * 128 -> chunk = 128
    const int bid = blockIdx.x;
    const int swz = (bid & 7) * 128 + (bid >> 3);

    const int pxi  = tid & 127;                 // pixel within row
    const int half = tid >> 7;                  // channel half
    const int cb   = half * 16;

    const int flat0 = swz * 128;
    const int b   = flat0 / HWc;
    const int row = flat0 - b * HWc;
    const int h   = row >> 7;                   // Wc == 128
    const int w   = pxi;
    const int p   = row + pxi;

    const unsigned short* k1b = k1pm + (size_t)b * HWc * 32;
    const unsigned short* vb  = vpm  + (size_t)b * HWc * 32;

    // ---- depthwise 3x3, own 16 channels ----
    float t[16];
#pragma unroll
    for (int e = 0; e < 16; ++e) t[e] = dwbs[cb + e];
#pragma unroll
    for (int i = 0; i < 3; ++i) {
        const int hh = h + i - 1;
#pragma unroll
        for (int j = 0; j < 3; ++j) {
            const int ww = w + j - 1;
            if (hh < 0 || hh >= Hc || ww < 0 || ww >= Wc) continue;
            const unsigned short* kr = k1b + (size_t)(hh * Wc + ww) * 32 + cb;
            const int ij = i * 3 + j;
#pragma unroll
            for (int qv = 0; qv < 2; ++qv) {
                const bf16x8 kv = __builtin_bit_cast(bf16x8, *(const s16x8*)(kr + qv * 8));
#pragma unroll
                for (int e = 0; e < 8; ++e)
                    t[qv * 8 + e] = fmaf((float)kv[e], dwt[ij][cb + qv * 8 + e],
                                         t[qv * 8 + e]);
            }
        }
    }

    // ---- partial 1x1 CK->9; exchange via LDS ----
#pragma unroll
    for (int kk = 0; kk < KKc; ++kk) {
        float a = (half == 0) ? k3bs[kk] : 0.f;
#pragma unroll
        for (int e = 0; e < 16; ++e)
            a = fmaf(k3s[kk][cb + e], t[e], a);
        plds[half][kk][pxi] = a;
    }
    __syncthreads();

    float logit[KKc];
#pragma unroll
    for (int kk = 0; kk < KKc; ++kk)
        logit[kk] = plds[0][kk][pxi] + plds[1][kk][pxi];

    float m = logit[0];
#pragma unroll
    for (int kk = 1; kk < KKc; ++kk) m = fmaxf(m, logit[kk]);
    float s = 0.f;
#pragma unroll
    for (int kk = 0; kk < KKc; ++kk) { logit[kk] = expf(logit[kk] - m); s += logit[kk]; }
    const float inv = 1.f / s;
#pragma unroll
    for (int kk = 0; kk < KKc; ++kk) logit[kk] *= inv;

    // ---- unfold-aggregate, own 16 v-channels ----
    float yv[16];
#pragma unroll
    for (int e = 0; e < 16; ++e) yv[e] = 0.f;
#pragma unroll
    for (int i = 0; i < 3; ++i) {
        const int hh = h + i - 1;
#pragma unroll
        for (int j = 0; j < 3; ++j) {
            const int ww = w + j - 1;
            if (hh < 0 || hh >= Hc || ww < 0 || ww >= Wc) continue;
            const unsigned short* vr = vb + (size_t)(hh * Wc + ww) * 32 + cb;
            const float wv = logit[i * 3 + j];
#pragma unroll
            for (int qv = 0; qv < 2; ++qv) {
                const bf16x8 vv = __builtin_bit_cast(bf16x8, *(const s16x8*)(vr + qv * 8));
#pragma unroll
                for (int e = 0; e < 8; ++e)
                    yv[qv * 8 + e] = fmaf(wv, (float)vv[e], yv[qv * 8 + e]);
            }
        }
    }

    // ---- write own half of y px-major bf16 (32 B) ----
    alignas(16) short ybf[16];
#pragma unroll
    for (int e = 0; e < 16; ++e) ybf[e] = (short)f2bf(yv[e]);
    unsigned short* yo = ypm + ((size_t)b * HWc + p) * 32 + cb;
    *(float4*)(yo)     = *(const float4*)&ybf[0];
    *(float4*)(yo + 8) = *(const float4*)&ybf[8];
}

// ---- Kernel 3: out conv + residual. 128 px/block, 1024 blocks, 32 KB LDS
//      (4 blocks/CU = 16 waves/CU). MFMA -> per-wave barrier-free LDS
//      transpose -> 512 B-contiguous x-loads / out-stores. ----
__global__ __launch_bounds__(256, 4) void ns_oconv(
    const float* __restrict__ x,
    const unsigned short* __restrict__ ypm,
    const unsigned short* __restrict__ owbf, const float* __restrict__ o_b,
    float* __restrict__ out)
{
    __shared__ float dlds[64 * 128];            // 32 KB: [och_local][px], swizzled

    const int tid = threadIdx.x;
    const int w   = tid >> 6;                   // wave 0..3
    const int l   = tid & 63;
    const int li  = l & 15;
    const int lk  = l >> 4;

    const int flat0 = blockIdx.x * 128;
    const int b  = flat0 / HWc;
    const int p0 = flat0 - b * HWc;

    // ---- 8 y A-frags, loaded once (A[m=px][k=cv]: lane li = px row) ----
    const unsigned short* yb = ypm + ((size_t)b * HWc + p0) * 32;
    bf16x8 yfrag[8];
#pragma unroll
    for (int pt = 0; pt < 8; ++pt)
        yfrag[pt] = __builtin_bit_cast(bf16x8,
            *(const s16x8*)(yb + (size_t)(pt * 16 + li) * 32 + lk * 8));

    const float* xb0 = x + (size_t)b * Cc * HWc + p0;
    float* ob0 = out + (size_t)b * Cc * HWc + p0;

    for (int pass = 0; pass < 4; ++pass) {
        const int och0 = pass * 64;

        // ---- phase A: 8 MFMAs, D -> LDS rows [w*16 .. w*16+15] (own rows) ----
        const int rowA = w * 16 + li;           // lane's D column och (local)
        const bf16x8 wfrag = __builtin_bit_cast(bf16x8,
            *(const s16x8*)(owbf + (size_t)(och0 + rowA) * 32 + lk * 8));
        float* dro = dlds + rowA * 128;
        const int sw = (li & 7) << 2;           // XOR swizzle (16B-granular)
#pragma unroll
        for (int pt = 0; pt < 8; ++pt) {
            f32x4 acc = {0.f, 0.f, 0.f, 0.f};
            acc = __builtin_amdgcn_mfma_f32_16x16x32_bf16(yfrag[pt], wfrag, acc, 0, 0, 0);
            const int col = (pt * 16 + lk * 4) ^ sw;   // px = pt*16+lk*4 .. +3
            *(f32x4*)(dro + col) = acc;
        }
        // no barrier: each wave reads back only the rows it wrote (same-wave
        // DS ordering is HW-guaranteed)

        // ---- phase B: batched 512 B-contiguous x-loads, LDS read, store ----
        float2 xvv[16];
#pragma unroll
        for (int r = 0; r < 16; ++r) {
            const int och = och0 + w * 16 + r;
            xvv[r] = *(const float2*)(xb0 + (size_t)och * HWc + l * 2);
        }
#pragma unroll
        for (int r = 0; r < 16; ++r) {
            const int row = w * 16 + r;
            const int och = och0 + row;
            const float bi = o_b[och];
            const int col = (l * 2) ^ ((row & 7) << 2);
            const float2 dv = *(const float2*)(dlds + row * 128 + col);
            float2 ov = { xvv[r].x + dv.x + bi, xvv[r].y + dv.y + bi };
            *(float2*)(ob0 + (size_t)och * HWc + l * 2) = ov;
        }
    }
}

extern "C" void kernel_launch(void* const* d_in, const int* in_sizes, int n_in,
                              void* d_out, int out_size, void* d_ws, size_t ws_size,
                              hipStream_t stream)
{
    const float* x    = (const float*)d_in[0];
    const float* k1_w = (const float*)d_in[1];
    const float* k1_b = (const float*)d_in[2];
    const float* dw_w = (const float*)d_in[3];
    const float* dw_b = (const float*)d_in[4];
    const float* k3_w = (const float*)d_in[5];
    const float* k3_b = (const float*)d_in[6];
    const float* v_w  = (const float*)d_in[7];
    const float* v_b  = (const float*)d_in[8];
    const float* o_w  = (const float*)d_in[9];
    const float* o_b  = (const float*)d_in[10];
    float* out = (float*)d_out;

    // workspace: k1pm (8.4MB) | vpm (8.4MB) | ypm (8.4MB) | owbf (16KB), bf16
    unsigned short* k1pm = (unsigned short*)d_ws;
    unsigned short* vpm  = k1pm + (size_t)Bc * HWc * 32;
    unsigned short* ypm  = vpm  + (size_t)Bc * HWc * 32;
    unsigned short* owbf = ypm  + (size_t)Bc * HWc * 32;

    const int npx = Bc * HWc;                   // 131072

    ns_k1v  <<<dim3(npx / 128), dim3(256), 0, stream>>>(x, k1_w, k1_b, v_w, v_b, o_w,
                                                        k1pm, vpm, owbf);
    ns_y    <<<dim3(npx / 128), dim3(256), 0, stream>>>(k1pm, vpm, dw_w, dw_b,
                                                        k3_w, k3_b, ypm);
    ns_oconv<<<dim3(npx / 128), dim3(256), 0, stream>>>(x, ypm, owbf, o_b, out);
}

// Round 16
// 82.628 us; speedup vs baseline: 1.4116x; 1.0966x over previous
//
#include <hip/hip_runtime.h>
#include <cmath>

namespace {
constexpr int Cc = 256, CKc = 32, CVc = 32, KKc = 9;
constexpr int Bc = 8, Hc = 128, Wc = 128, HWc = Hc * Wc;

typedef __attribute__((ext_vector_type(8))) short   s16x8;
typedef __attribute__((ext_vector_type(8))) __bf16  bf16x8;
typedef __attribute__((ext_vector_type(4))) float   f32x4;

__device__ inline unsigned short f2bf(float f) {   // RNE f32 -> bf16 bits
    union { float f; unsigned u; } v; v.f = f;
    unsigned u = v.u + 0x7fffu + ((v.u >> 16) & 1u);
    return (unsigned short)(u >> 16);
}
}

// ---- Kernel 1: k1 = relu(W_k1 x + b), v = W_v x + b  via bf16 MFMA ----
// Outputs PX-MAJOR bf16: k1pm/vpm [b][hw][32]. Block 0 also converts o_w -> bf16.
__global__ __launch_bounds__(256) void ns_k1v(
    const float* __restrict__ x,
    const float* __restrict__ k1_w, const float* __restrict__ k1_b,
    const float* __restrict__ v_w,  const float* __restrict__ v_b,
    const float* __restrict__ o_w,
    unsigned short* __restrict__ k1pm, unsigned short* __restrict__ vpm,
    unsigned short* __restrict__ owbf)
{
    constexpr int LP = 72;                      // row stride (shorts): 144 B
    __shared__ short w_bf[64][LP];              // chunk of W (64 o x 64 ch)
    __shared__ short x_bf[128][LP];             // chunk of X (128 px x 64 ch)

    const int tid = threadIdx.x;
    const int l   = tid & 63;
    const int li  = l & 15;
    const int lk  = l >> 4;
    const int wv  = __builtin_amdgcn_readfirstlane(tid >> 6);

    // one-time o_w -> bf16 (owbf consumed only after this kernel completes)
    if (blockIdx.x == 0) {
        for (int i = tid * 4; i < Cc * CVc; i += 256 * 4) {
            const float4 f = *(const float4*)(o_w + i);
            const unsigned a = (unsigned)f2bf(f.x) | ((unsigned)f2bf(f.y) << 16);
            const unsigned c = (unsigned)f2bf(f.z) | ((unsigned)f2bf(f.w) << 16);
            *(uint2*)(owbf + i) = make_uint2(a, c);
        }
    }

    const int flat0 = blockIdx.x * 128;
    const int b  = flat0 / HWc;
    const int pp = flat0 - b * HWc;
    const float* xb = x + (size_t)b * Cc * HWc + pp;

    const int sp2 = (tid & 63) * 2;             // X staging: pixel pair base
    const int scg = tid >> 6;                   // X staging: ch group (16 ch)
    const int so   = tid & 63;                  // W staging: output row
    const int swc0 = (tid >> 6) * 16;
    const float* wsrc = (so < 32) ? (k1_w + (size_t)so * Cc)
                                  : (v_w + (size_t)(so - 32) * Cc);

    f32x4 acc[8];
    const f32x4 zero = {0.f, 0.f, 0.f, 0.f};
#pragma unroll
    for (int i = 0; i < 8; ++i) acc[i] = zero;

    for (int c0 = 0; c0 < Cc; c0 += 64) {
        __syncthreads();
        // ---- stage W chunk ----
        {
            alignas(16) short tmp[16];
#pragma unroll
            for (int f = 0; f < 4; ++f) {
                const float4 fv = *(const float4*)(wsrc + c0 + swc0 + f * 4);
                tmp[f*4+0] = f2bf(fv.x); tmp[f*4+1] = f2bf(fv.y);
                tmp[f*4+2] = f2bf(fv.z); tmp[f*4+3] = f2bf(fv.w);
            }
            *(s16x8*)&w_bf[so][swc0]     = *(const s16x8*)&tmp[0];
            *(s16x8*)&w_bf[so][swc0 + 8] = *(const s16x8*)&tmp[8];
        }
        // ---- stage X chunk: 2 px x 16 ch per thread, 16 batched float2 loads ----
        {
            float2 xv2[16];
#pragma unroll
            for (int cq = 0; cq < 16; ++cq)
                xv2[cq] = *(const float2*)(xb + (size_t)(c0 + scg * 16 + cq) * HWc + sp2);
            alignas(16) short ta[16], tb[16];
#pragma unroll
            for (int cq = 0; cq < 16; ++cq) {
                ta[cq] = f2bf(xv2[cq].x);
                tb[cq] = f2bf(xv2[cq].y);
            }
            *(s16x8*)&x_bf[sp2    ][scg * 16]     = *(const s16x8*)&ta[0];
            *(s16x8*)&x_bf[sp2    ][scg * 16 + 8] = *(const s16x8*)&ta[8];
            *(s16x8*)&x_bf[sp2 + 1][scg * 16]     = *(const s16x8*)&tb[0];
            *(s16x8*)&x_bf[sp2 + 1][scg * 16 + 8] = *(const s16x8*)&tb[8];
        }
        __syncthreads();

#pragma unroll
        for (int ks = 0; ks < 2; ++ks) {
            const s16x8 ar = *(const s16x8*)&w_bf[wv * 16 + li][ks * 32 + lk * 8];
            const bf16x8 af = __builtin_bit_cast(bf16x8, ar);
#pragma unroll
            for (int pt = 0; pt < 8; ++pt) {
                const s16x8 br = *(const s16x8*)&x_bf[pt * 16 + li][ks * 32 + lk * 8];
                acc[pt] = __builtin_amdgcn_mfma_f32_16x16x32_bf16(
                    af, __builtin_bit_cast(bf16x8, br), acc[pt], 0, 0, 0);
            }
        }
    }

    const bool is_k = wv < 2;
    const int obase = wv * 16 + lk * 4;
    const int chq = is_k ? obase : obase - 32;
    float bias[4];
#pragma unroll
    for (int r = 0; r < 4; ++r)
        bias[r] = is_k ? k1_b[obase + r] : v_b[obase + r - 32];
    unsigned short* dstb = is_k ? k1pm : vpm;

#pragma unroll
    for (int pt = 0; pt < 8; ++pt) {
        const size_t row = (size_t)b * HWc + pp + pt * 16 + li;
        float v0 = acc[pt][0] + bias[0], v1 = acc[pt][1] + bias[1];
        float v2 = acc[pt][2] + bias[2], v3 = acc[pt][3] + bias[3];
        if (is_k) {
            v0 = fmaxf(v0, 0.f); v1 = fmaxf(v1, 0.f);
            v2 = fmaxf(v2, 0.f); v3 = fmaxf(v3, 0.f);
        }
        const unsigned p01 = (unsigned)f2bf(v0) | ((unsigned)f2bf(v1) << 16);
        const unsigned p23 = (unsigned)f2bf(v2) | ((unsigned)f2bf(v3) << 16);
        *(uint2*)(dstb + row * 32 + chq) = make_uint2(p01, p23);
    }
}

// ---- Kernel 2 (fused): y-gen (dw3x3 + 1x1->9 + softmax + unfold, 2 thr/px,
//      y kept in LDS) then out conv + residual via MFMA with per-wave
//      barrier-free LDS transpose epilogue. 256 thr / 128 px, 1024 blocks.
//      Phase-1 scratch (plds 9K + ylds 10K) aliases the 32K dlds buffer. ----
__global__ __launch_bounds__(256, 4) void ns_yoc(
    const float* __restrict__ x,
    const unsigned short* __restrict__ k1pm,
    const unsigned short* __restrict__ vpm,
    const float* __restrict__ dw_w, const float* __restrict__ dw_b,
    const float* __restrict__ k3_w, const float* __restrict__ k3_b,
    const unsigned short* __restrict__ owbf, const float* __restrict__ o_b,
    float* __restrict__ out)
{
    __shared__ alignas(16) float dlds[64 * 128];    // 32 KB shared pool
    float* plds = dlds;                              // [2][9][128] = 9 KB (phase 1)
    short* ylds = (short*)(dlds + 2 * KKc * 128);    // [128][40]   = 10 KB (phase 1)
    __shared__ float dwt[KKc][CKc];
    __shared__ float k3s[KKc][CKc];
    __shared__ float dwbs[CKc];
    __shared__ float k3bs[KKc];

    const int tid = threadIdx.x;
    for (int idx = tid; idx < CKc * KKc; idx += 256) {
        const int ck = idx / KKc, kk = idx - ck * KKc;
        dwt[kk][ck] = dw_w[idx];
        ((float*)k3s)[idx] = k3_w[idx];
    }
    if (tid < CKc) dwbs[tid] = dw_b[tid];
    if (tid < KKc) k3bs[tid] = k3_b[tid];
    __syncthreads();

    // XCD-bijective swizzle: nwg = 1024 = 8 * 128 -> chunk = 128
    const int bid = blockIdx.x;
    const int swz = (bid & 7) * 128 + (bid >> 3);

    const int pxi  = tid & 127;                 // pixel within row
    const int half = tid >> 7;                  // channel half
    const int cb   = half * 16;

    const int flat0 = swz * 128;
    const int b   = flat0 / HWc;
    const int row = flat0 - b * HWc;            // px offset of this image row
    const int h   = row >> 7;                   // Wc == 128
    const int w   = pxi;

    const unsigned short* k1b = k1pm + (size_t)b * HWc * 32;
    const unsigned short* vb  = vpm  + (size_t)b * HWc * 32;

    // ---- phase 1a: depthwise 3x3, own 16 channels ----
    float t[16];
#pragma unroll
    for (int e = 0; e < 16; ++e) t[e] = dwbs[cb + e];
#pragma unroll
    for (int i = 0; i < 3; ++i) {
        const int hh = h + i - 1;
#pragma unroll
        for (int j = 0; j < 3; ++j) {
            const int ww = w + j - 1;
            if (hh < 0 || hh >= Hc || ww < 0 || ww >= Wc) continue;
            const unsigned short* kr = k1b + (size_t)(hh * Wc + ww) * 32 + cb;
            const int ij = i * 3 + j;
#pragma unroll
            for (int qv = 0; qv < 2; ++qv) {
                const bf16x8 kv = __builtin_bit_cast(bf16x8, *(const s16x8*)(kr + qv * 8));
#pragma unroll
                for (int e = 0; e < 8; ++e)
                    t[qv * 8 + e] = fmaf((float)kv[e], dwt[ij][cb + qv * 8 + e],
                                         t[qv * 8 + e]);
            }
        }
    }

    // ---- phase 1b: partial 1x1 CK->9; exchange via plds ----
#pragma unroll
    for (int kk = 0; kk < KKc; ++kk) {
        float a = (half == 0) ? k3bs[kk] : 0.f;
#pragma unroll
        for (int e = 0; e < 16; ++e)
            a = fmaf(k3s[kk][cb + e], t[e], a);
        plds[(half * KKc + kk) * 128 + pxi] = a;
    }
    __syncthreads();

    float logit[KKc];
#pragma unroll
    for (int kk = 0; kk < KKc; ++kk)
        logit[kk] = plds[kk * 128 + pxi] + plds[(KKc + kk) * 128 + pxi];

    float m = logit[0];
#pragma unroll
    for (int kk = 1; kk < KKc; ++kk) m = fmaxf(m, logit[kk]);
    float s = 0.f;
#pragma unroll
    for (int kk = 0; kk < KKc; ++kk) { logit[kk] = expf(logit[kk] - m); s += logit[kk]; }
    const float inv = 1.f / s;
#pragma unroll
    for (int kk = 0; kk < KKc; ++kk) logit[kk] *= inv;

    // ---- phase 1c: unfold-aggregate, own 16 v-channels ----
    float yv[16];
#pragma unroll
    for (int e = 0; e < 16; ++e) yv[e] = 0.f;
#pragma unroll
    for (int i = 0; i < 3; ++i) {
        const int hh = h + i - 1;
#pragma unroll
        for (int j = 0; j < 3; ++j) {
            const int ww = w + j - 1;
            if (hh < 0 || hh >= Hc || ww < 0 || ww >= Wc) continue;
            const unsigned short* vr = vb + (size_t)(hh * Wc + ww) * 32 + cb;
            const float wv = logit[i * 3 + j];
#pragma unroll
            for (int qv = 0; qv < 2; ++qv) {
                const bf16x8 vv = __builtin_bit_cast(bf16x8, *(const s16x8*)(vr + qv * 8));
#pragma unroll
                for (int e = 0; e < 8; ++e)
                    yv[qv * 8 + e] = fmaf(wv, (float)vv[e], yv[qv * 8 + e]);
            }
        }
    }

    // y -> ylds bf16 [px][40] (own half: 32 B; disjoint from plds region)
    {
        alignas(16) short ybf[16];
#pragma unroll
        for (int e = 0; e < 16; ++e) ybf[e] = (short)f2bf(yv[e]);
        short* yo = ylds + pxi * 40 + cb;
        *(float4*)(yo)     = *(const float4*)&ybf[0];
        *(float4*)(yo + 8) = *(const float4*)&ybf[8];
    }
    __syncthreads();                            // ylds complete

    // ---- phase 2: out conv + residual (R15 ns_oconv body, y from LDS) ----
    const int wv2 = tid >> 6;                   // wave 0..3
    const int l   = tid & 63;
    const int li  = l & 15;
    const int lk  = l >> 4;

    bf16x8 yfrag[8];
#pragma unroll
    for (int pt = 0; pt < 8; ++pt)
        yfrag[pt] = __builtin_bit_cast(bf16x8,
            *(const s16x8*)(ylds + (pt * 16 + li) * 40 + lk * 8));
    __syncthreads();                            // all yfrags read; dlds may clobber

    const float* xb0 = x + (size_t)b * Cc * HWc + row;
    float* ob0 = out + (size_t)b * Cc * HWc + row;

    for (int pass = 0; pass < 4; ++pass) {
        const int och0 = pass * 64;

        // phase A: 8 MFMAs, D -> own LDS rows (barrier-free per-wave transpose)
        const int rowA = wv2 * 16 + li;
        const bf16x8 wfrag = __builtin_bit_cast(bf16x8,
            *(const s16x8*)(owbf + (size_t)(och0 + rowA) * 32 + lk * 8));
        float* dro = dlds + rowA * 128;
        const int sw = (li & 7) << 2;
#pragma unroll
        for (int pt = 0; pt < 8; ++pt) {
            f32x4 acc = {0.f, 0.f, 0.f, 0.f};
            acc = __builtin_amdgcn_mfma_f32_16x16x32_bf16(yfrag[pt], wfrag, acc, 0, 0, 0);
            const int col = (pt * 16 + lk * 4) ^ sw;
            *(f32x4*)(dro + col) = acc;
        }

        // phase B: batched 512 B-contiguous x-loads, LDS read-back, store
        float2 xvv[16];
#pragma unroll
        for (int r = 0; r < 16; ++r) {
            const int och = och0 + wv2 * 16 + r;
            xvv[r] = *(const float2*)(xb0 + (size_t)och * HWc + l * 2);
        }
#pragma unroll
        for (int r = 0; r < 16; ++r) {
            const int rw = wv2 * 16 + r;
            const int och = och0 + rw;
            const float bi = o_b[och];
            const int col = (l * 2) ^ ((rw & 7) << 2);
            const float2 dv = *(const float2*)(dlds + rw * 128 + col);
            float2 ov = { xvv[r].x + dv.x + bi, xvv[r].y + dv.y + bi };
            *(float2*)(ob0 + (size_t)och * HWc + l * 2) = ov;
        }
    }
}

extern "C" void kernel_launch(void* const* d_in, const int* in_sizes, int n_in,
                              void* d_out, int out_size, void* d_ws, size_t ws_size,
                              hipStream_t stream)
{
    const float* x    = (const float*)d_in[0];
    const float* k1_w = (const float*)d_in[1];
    const float* k1_b = (const float*)d_in[2];
    const float* dw_w = (const float*)d_in[3];
    const float* dw_b = (const float*)d_in[4];
    const float* k3_w = (const float*)d_in[5];
    const float* k3_b = (const float*)d_in[6];
    const float* v_w  = (const float*)d_in[7];
    const float* v_b  = (const float*)d_in[8];
    const float* o_w  = (const float*)d_in[9];
    const float* o_b  = (const float*)d_in[10];
    float* out = (float*)d_out;

    // workspace: k1pm (8.4MB) | vpm (8.4MB) | owbf (16KB), bf16
    unsigned short* k1pm = (unsigned short*)d_ws;
    unsigned short* vpm  = k1pm + (size_t)Bc * HWc * 32;
    unsigned short* owbf = vpm  + (size_t)Bc * HWc * 32;

    const int npx = Bc * HWc;                   // 131072

    ns_k1v<<<dim3(npx / 128), dim3(256), 0, stream>>>(x, k1_w, k1_b, v_w, v_b, o_w,
                                                      k1pm, vpm, owbf);
    ns_yoc<<<dim3(npx / 128), dim3(256), 0, stream>>>(x, k1pm, vpm, dw_w, dw_b,
                                                      k3_w, k3_b, owbf, o_b, out);
}